// Round 1
// baseline (819.556 us; speedup 1.0000x reference)
//
#include <hip/hip_runtime.h>

// LinearAttention: B=2, C=96, H=64, W=64, D=32 -> N=131072 tokens, 8 heads x hd=12
// x layout in memory: [B, C, N] with N contiguous (N = 2^17).
//
// Math (fp32 throughout):
//   kl[b,n,c] = sum_c' x[b,c',n] * Wk[c,c']      (nn.Linear: x @ W^T)
//   S[b,c]    = sum_n exp(kl[b,n,c])             (k softmax over N; max-sub cancels)
//   ctxU[b,h,d,e] = sum_n exp(kl[n,h*12+d]) * vl[n,h*12+e]
//   M[b,(h,d),o]  = sum_e (ctxU/S[h*12+d]) * Wproj[o, h*12+e]   (Wproj folded in)
//   out[b,o,n] = sum_{h,d} softmax_d(ql[n,h,:])[d] * M[b,(h,d),o]
//
// ws layout (floats):
//   part[8][B][1248]  @ 0       (1152 ctx + 96 S per (partial,b))  -> zeroed via memset
//   Mt[B][96][96]     @ 19968   (Mt[b][o][r], r = h*12+d; fully overwritten by kB)

#define NTOK 131072
#define NSH 17          // log2(NTOK)

__global__ __launch_bounds__(256, 2)
void kA(const float* __restrict__ x, const float* __restrict__ Wk,
        const float* __restrict__ Wv, float* __restrict__ part) {
  constexpr int P = 258;                 // 258 % 32 == 2 -> conflict-free float2 dots
  __shared__ float ke_s[12 * P];
  __shared__ float vl_s[12 * P];
  __shared__ float ctx_s[8 * 144];       // per-block ctx accumulator
  __shared__ float ss_s[96];             // per-block k-exp column sums
  const int tid = threadIdx.x;
  const int bb = blockIdx.x & 255;       // 256 block-groups per batch
  const int b  = blockIdx.x >> 8;        // 512 blocks total

  for (int i = tid; i < 1152; i += 256) ctx_s[i] = 0.f;
  if (tid < 96) ss_s[tid] = 0.f;
  __syncthreads();

  for (int tile = 0; tile < 2; ++tile) {
    const int n = bb * 512 + tile * 256 + tid;
    // stage this token's 96 channel values in VGPRs (coalesced along n)
    float xr[96];
#pragma unroll
    for (int c = 0; c < 96; ++c) xr[c] = x[((size_t)(b * 96 + c) << NSH) + n];

    for (int h = 0; h < 8; ++h) {
      const float* __restrict__ wk = Wk + h * 12 * 96;
      const float* __restrict__ wv = Wv + h * 12 * 96;
      // ---- k pass: 12 logits, weights via uniform (scalar) loads ----
      {
        float ka[12];
#pragma unroll
        for (int j = 0; j < 12; ++j) ka[j] = 0.f;
#pragma unroll
        for (int c = 0; c < 96; ++c) {
          const float xc = xr[c];
#pragma unroll
          for (int j = 0; j < 12; ++j) ka[j] = fmaf(xc, wk[j * 96 + c], ka[j]);
        }
#pragma unroll
        for (int j = 0; j < 12; ++j) ke_s[j * P + tid] = __expf(ka[j]);
      }
      // ---- v pass ----
      {
        float va[12];
#pragma unroll
        for (int j = 0; j < 12; ++j) va[j] = 0.f;
#pragma unroll
        for (int c = 0; c < 96; ++c) {
          const float xc = xr[c];
#pragma unroll
          for (int j = 0; j < 12; ++j) va[j] = fmaf(xc, wv[j * 96 + c], va[j]);
        }
#pragma unroll
        for (int j = 0; j < 12; ++j) vl_s[j * P + tid] = va[j];
      }
      __syncthreads();
      // ---- block-level reduction: 144 outer-product dots + 12 column sums ----
      if (tid < 144) {
        const int d = tid / 12, e = tid % 12;
        const float* kp = &ke_s[d * P];
        const float* vp = &vl_s[e * P];
        float a0 = 0.f, a1 = 0.f;
        for (int t = 0; t < 256; t += 2) {
          const float2 k2 = *(const float2*)(kp + t);
          const float2 v2 = *(const float2*)(vp + t);
          a0 = fmaf(k2.x, v2.x, a0);
          a1 = fmaf(k2.y, v2.y, a1);
        }
        ctx_s[h * 144 + tid] += a0 + a1;      // unique writer per entry
      } else if (tid < 156) {
        const int j = tid - 144;
        const float* kp = &ke_s[j * P];
        float a0 = 0.f, a1 = 0.f;
        for (int t = 0; t < 256; t += 2) {
          const float2 k2 = *(const float2*)(kp + t);
          a0 += k2.x; a1 += k2.y;
        }
        ss_s[h * 12 + j] += a0 + a1;
      }
      __syncthreads();
    }
  }
  // flush to one of 8 partial buffers (spreads atomic contention 8x)
  const int p = blockIdx.x & 7;
  float* dst = part + (size_t)(p * 2 + b) * 1248;
  for (int i = tid; i < 1152; i += 256) atomicAdd(&dst[i], ctx_s[i]);
  if (tid < 96) atomicAdd(&dst[1152 + tid], ss_s[tid]);
}

__global__ void kB(const float* __restrict__ part, const float* __restrict__ Wproj,
                   float* __restrict__ Mt) {
  const int g = blockIdx.x * 256 + threadIdx.x;   // 2*96*96 = 18432 exactly
  if (g >= 2 * 96 * 96) return;
  const int b = g / (96 * 96);
  const int rem = g % (96 * 96);
  const int o = rem / 96;
  const int r = rem % 96;        // r = h*12+d
  const int h = r / 12, d = r % 12;
  float s = 0.f;
#pragma unroll
  for (int p = 0; p < 8; ++p) s += part[(size_t)(p * 2 + b) * 1248 + 1152 + r];
  float acc = 0.f;
#pragma unroll
  for (int e = 0; e < 12; ++e) {
    float ce = 0.f;
#pragma unroll
    for (int p = 0; p < 8; ++p)
      ce += part[(size_t)(p * 2 + b) * 1248 + h * 144 + d * 12 + e];
    acc = fmaf(ce, Wproj[o * 96 + h * 12 + e], acc);
  }
  Mt[(size_t)(b * 96 + o) * 96 + r] = acc / s;
}

__global__ __launch_bounds__(256, 2)
void kC(const float* __restrict__ x, const float* __restrict__ Wq,
        const float* __restrict__ Mt, float* __restrict__ out) {
  const int tid = threadIdx.x;
  const int bb = blockIdx.x & 511;       // 512 blocks per batch
  const int b  = blockIdx.x >> 9;
  const int n  = bb * 256 + tid;

  float xr[96];
#pragma unroll
  for (int c = 0; c < 96; ++c) xr[c] = x[((size_t)(b * 96 + c) << NSH) + n];

  float q[96];
  for (int h = 0; h < 8; ++h) {
    const float* __restrict__ wq = Wq + h * 12 * 96;
    float ql[12];
#pragma unroll
    for (int j = 0; j < 12; ++j) ql[j] = 0.f;
#pragma unroll
    for (int c = 0; c < 96; ++c) {
      const float xc = xr[c];
#pragma unroll
      for (int j = 0; j < 12; ++j) ql[j] = fmaf(xc, wq[j * 96 + c], ql[j]);
    }
    float m = ql[0];
#pragma unroll
    for (int j = 1; j < 12; ++j) m = fmaxf(m, ql[j]);
    float s = 0.f;
#pragma unroll
    for (int j = 0; j < 12; ++j) { ql[j] = __expf(ql[j] - m); s += ql[j]; }
    const float invs = 1.0f / s;
#pragma unroll
    for (int j = 0; j < 12; ++j) q[h * 12 + j] = ql[j] * invs;
  }

  const float* __restrict__ mb = Mt + (size_t)b * 9216;   // Mt[b][o][r], r contiguous
  for (int o = 0; o < 96; ++o) {
    float acc = 0.f;
#pragma unroll
    for (int r = 0; r < 96; ++r) acc = fmaf(q[r], mb[o * 96 + r], acc);
    out[((size_t)(b * 96 + o) << NSH) + n] = acc;
  }
}

extern "C" void kernel_launch(void* const* d_in, const int* in_sizes, int n_in,
                              void* d_out, int out_size, void* d_ws, size_t ws_size,
                              hipStream_t stream) {
  const float* x     = (const float*)d_in[0];
  const float* Wq    = (const float*)d_in[1];
  const float* Wk    = (const float*)d_in[2];
  const float* Wv    = (const float*)d_in[3];
  const float* Wproj = (const float*)d_in[4];
  float* out = (float*)d_out;
  float* ws  = (float*)d_ws;

  float* part = ws;              // 8*2*1248 = 19968 floats
  float* Mt   = ws + 19968;      // 2*96*96  = 18432 floats

  hipMemsetAsync(part, 0, 19968 * sizeof(float), stream);
  kA<<<512, 256, 0, stream>>>(x, Wk, Wv, part);
  kB<<<72, 256, 0, stream>>>(part, Wproj, Mt);
  kC<<<1024, 256, 0, stream>>>(x, Wq, Mt, out);
}

// Round 2
// 264.722 us; speedup vs baseline: 3.0959x; 3.0959x over previous
//
#include <hip/hip_runtime.h>

// LinearAttention MI355X: B=2, C=96, N=131072 (x stored [B,C,N], N contiguous),
// 8 heads x hd=12. MFMA fp16 rewrite.
//
//   kl = Wk·X, ke = exp(kl); vl = Wv·X           (p1: per-128-token tile GEMMs)
//   ctx[h,d,e] = sum_n ke[h12+d][n]·vl[h12+e][n] (p1: 16x16x32 MFMA over tokens)
//   S[c] = sum_n ke[c][n]                         (p1: VALU row sums)
//   M[o][r] = sum_e (ctx/S)·Wproj[o][h12+e]       (kB: tiny)
//   q = softmax_head(Wq·X); out[o][n] = sum_r M[o][r]·q[r][n]   (p3)
//
// Fragment layouts (gfx950, verified learn_hip m89/m118/m120):
//   A[m=lane&15][k=quad*8+j], B[k=quad*8+j][n=lane&15], C/D row=quad*4+reg col=lane&15

typedef _Float16 half_t;
typedef _Float16 half8 __attribute__((ext_vector_type(8)));
typedef float f32x4 __attribute__((ext_vector_type(4)));

#define MFMA16 __builtin_amdgcn_mfma_f32_16x16x32_f16
#define NSH 17
#define NP 16   // partial reduction buffers

// ---------------- pass 1: k,v GEMMs + context ----------------
__global__ __launch_bounds__(256, 2)
void p1(const float* __restrict__ x, const float* __restrict__ Wk,
        const float* __restrict__ Wv, float* __restrict__ part) {
  // LDS map (bytes): [0: xs 128x104 f16 = 26624][26624: wsm 96x104 f16 = 19968]
  //                  [46592: ke 100x136 f16 = 27200]   total 73792
  // vl (100x136=27200) overlays [0..27200) after all xs/wsm reads complete.
  __shared__ __align__(16) char smem[73792];
  half_t* xs  = (half_t*)smem;
  half_t* wsm = (half_t*)(smem + 26624);
  half_t* vl  = (half_t*)smem;
  half_t* ke  = (half_t*)(smem + 46592);

  const int tid  = threadIdx.x;
  const int lane = tid & 63, l15 = lane & 15, quad = lane >> 4, wid = tid >> 6;
  const int b  = blockIdx.x >> 10;
  const int n0 = (blockIdx.x & 1023) << 7;

  { // stage x tile -> xs[n][c] fp16 (global reads coalesced along n)
    const int n = tid & 127, cg = tid >> 7;
    const float* xb = x + (((size_t)(b * 96 + cg * 48)) << NSH) + n0 + n;
#pragma unroll
    for (int i = 0; i < 48; ++i)
      xs[n * 104 + cg * 48 + i] = (half_t)xb[(size_t)i << NSH];
  }
#pragma unroll
  for (int i = 0; i < 36; ++i) { // stage Wk -> wsm[o][c]
    int id = i * 256 + tid; int o = id / 96, c = id - o * 96;
    wsm[o * 104 + c] = (half_t)Wk[id];
  }
  __syncthreads();

  f32x4 acc[6][2];
  // ---- k GEMM: D[c_out][n] ----
#pragma unroll
  for (int rt = 0; rt < 6; ++rt)
#pragma unroll
    for (int ct = 0; ct < 2; ++ct) acc[rt][ct] = (f32x4){0.f, 0.f, 0.f, 0.f};
#pragma unroll
  for (int ks = 0; ks < 3; ++ks) {
    half8 af[6], bf[2];
#pragma unroll
    for (int rt = 0; rt < 6; ++rt)
      af[rt] = *(const half8*)&wsm[(rt * 16 + l15) * 104 + ks * 32 + quad * 8];
#pragma unroll
    for (int ct = 0; ct < 2; ++ct)
      bf[ct] = *(const half8*)&xs[((wid * 2 + ct) * 16 + l15) * 104 + ks * 32 + quad * 8];
#pragma unroll
    for (int rt = 0; rt < 6; ++rt)
#pragma unroll
      for (int ct = 0; ct < 2; ++ct)
        acc[rt][ct] = MFMA16(af[rt], bf[ct], acc[rt][ct], 0, 0, 0);
  }
  // k epilogue: exp -> ke[c][n]
#pragma unroll
  for (int rt = 0; rt < 6; ++rt)
#pragma unroll
    for (int ct = 0; ct < 2; ++ct)
#pragma unroll
      for (int i = 0; i < 4; ++i) {
        int row = rt * 16 + quad * 4 + i;
        int col = (wid * 2 + ct) * 16 + l15;
        ke[row * 136 + col] = (half_t)__expf(acc[rt][ct][i]);
      }
  __syncthreads();   // wsm reads done -> safe to overwrite with Wv

#pragma unroll
  for (int i = 0; i < 36; ++i) {
    int id = i * 256 + tid; int o = id / 96, c = id - o * 96;
    wsm[o * 104 + c] = (half_t)Wv[id];
  }
  __syncthreads();

  // ---- v GEMM ----
#pragma unroll
  for (int rt = 0; rt < 6; ++rt)
#pragma unroll
    for (int ct = 0; ct < 2; ++ct) acc[rt][ct] = (f32x4){0.f, 0.f, 0.f, 0.f};
#pragma unroll
  for (int ks = 0; ks < 3; ++ks) {
    half8 af[6], bf[2];
#pragma unroll
    for (int rt = 0; rt < 6; ++rt)
      af[rt] = *(const half8*)&wsm[(rt * 16 + l15) * 104 + ks * 32 + quad * 8];
#pragma unroll
    for (int ct = 0; ct < 2; ++ct)
      bf[ct] = *(const half8*)&xs[((wid * 2 + ct) * 16 + l15) * 104 + ks * 32 + quad * 8];
#pragma unroll
    for (int rt = 0; rt < 6; ++rt)
#pragma unroll
      for (int ct = 0; ct < 2; ++ct)
        acc[rt][ct] = MFMA16(af[rt], bf[ct], acc[rt][ct], 0, 0, 0);
  }
  __syncthreads();   // ALL xs/wsm reads done -> vl may overlay them
#pragma unroll
  for (int rt = 0; rt < 6; ++rt)
#pragma unroll
    for (int ct = 0; ct < 2; ++ct)
#pragma unroll
      for (int i = 0; i < 4; ++i) {
        int row = rt * 16 + quad * 4 + i;
        int col = (wid * 2 + ct) * 16 + l15;
        vl[row * 136 + col] = (half_t)acc[rt][ct][i];
      }
  __syncthreads();

  // ---- context via MFMA over tokens: wave wid handles heads 2w, 2w+1 ----
  // ctx[d][e] = sum_n ke[h12+d][n] * vl[h12+e][n]
  // A[m=d][k=n] = ke row (h12 + lane&15); B[k=n][col=e] = vl row (h12 + lane&15).
  // Rows 96..99 (h=7, m>=12) are garbage but only pollute D[m>=12]/[e>=12] (unread).
  float* dst = part + (size_t)((blockIdx.x & (NP - 1)) * 2 + b) * 1248;
#pragma unroll
  for (int hh = 0; hh < 2; ++hh) {
    const int h = wid * 2 + hh;
    f32x4 c = (f32x4){0.f, 0.f, 0.f, 0.f};
#pragma unroll
    for (int ks = 0; ks < 4; ++ks) {
      half8 a  = *(const half8*)&ke[(h * 12 + l15) * 136 + ks * 32 + quad * 8];
      half8 bv = *(const half8*)&vl[(h * 12 + l15) * 136 + ks * 32 + quad * 8];
      c = MFMA16(a, bv, c, 0, 0, 0);
    }
#pragma unroll
    for (int i = 0; i < 4; ++i) {
      int d = quad * 4 + i, e = l15;
      if (d < 12 && e < 12) atomicAdd(&dst[h * 144 + d * 12 + e], c[i]);
    }
  }
  // ---- S row sums (threads 0..95): S[c] = sum_n ke[c][n] ----
  if (tid < 96) {
    float s = 0.f;
#pragma unroll
    for (int j = 0; j < 16; ++j) {
      half8 v = *(const half8*)&ke[tid * 136 + j * 8];
#pragma unroll
      for (int e = 0; e < 8; ++e) s += (float)v[e];
    }
    atomicAdd(&dst[1152 + tid], s);
  }
}

// ---------------- pass 2: fold Wproj into tiny context ----------------
__global__ void kB(const float* __restrict__ part, const float* __restrict__ Wproj,
                   float* __restrict__ Mt) {
  const int g = blockIdx.x * 256 + threadIdx.x;   // 2*96*96 = 18432 exactly
  const int b = g / (96 * 96);
  const int rem = g % (96 * 96);
  const int o = rem / 96;
  const int r = rem % 96;        // r = h*12+d
  const int h = r / 12, d = r % 12;
  float s = 0.f;
#pragma unroll
  for (int p = 0; p < NP; ++p) s += part[(size_t)(p * 2 + b) * 1248 + 1152 + r];
  float acc = 0.f;
#pragma unroll
  for (int e = 0; e < 12; ++e) {
    float ce = 0.f;
#pragma unroll
    for (int p = 0; p < NP; ++p)
      ce += part[(size_t)(p * 2 + b) * 1248 + h * 144 + d * 12 + e];
    acc = fmaf(ce, Wproj[o * 96 + h * 12 + e], acc);
  }
  Mt[(size_t)(b * 96 + o) * 96 + r] = acc / s;
}

// ---------------- pass 3: q GEMM + softmax + out GEMM ----------------
__global__ __launch_bounds__(256, 2)
void p3(const float* __restrict__ x, const float* __restrict__ Wq,
        const float* __restrict__ Mt, float* __restrict__ out) {
  // LDS map: [0: xs 128x104=26624][26624: wsm(Wq) 19968][46592: Ms 96x104=19968]
  // qs (128x104 f16, [n][r]) overlays [0..26624) after q-GEMM.   total 66560
  __shared__ __align__(16) char smem[66560];
  half_t* xs  = (half_t*)smem;
  half_t* wsm = (half_t*)(smem + 26624);
  half_t* Ms  = (half_t*)(smem + 46592);
  half_t* qs  = (half_t*)smem;

  const int tid  = threadIdx.x;
  const int lane = tid & 63, l15 = lane & 15, quad = lane >> 4, wid = tid >> 6;
  const int b  = blockIdx.x >> 10;
  const int n0 = (blockIdx.x & 1023) << 7;

  { // stage x tile
    const int n = tid & 127, cg = tid >> 7;
    const float* xb = x + (((size_t)(b * 96 + cg * 48)) << NSH) + n0 + n;
#pragma unroll
    for (int i = 0; i < 48; ++i)
      xs[n * 104 + cg * 48 + i] = (half_t)xb[(size_t)i << NSH];
  }
#pragma unroll
  for (int i = 0; i < 36; ++i) { // Wq
    int id = i * 256 + tid; int o = id / 96, c = id - o * 96;
    wsm[o * 104 + c] = (half_t)Wq[id];
  }
  {
    const float* mtb = Mt + (size_t)b * 9216;
#pragma unroll
    for (int i = 0; i < 36; ++i) { // M
      int id = i * 256 + tid; int o = id / 96, r = id - o * 96;
      Ms[o * 104 + r] = (half_t)mtb[id];
    }
  }
  __syncthreads();

  f32x4 acc[6][2];
#pragma unroll
  for (int rt = 0; rt < 6; ++rt)
#pragma unroll
    for (int ct = 0; ct < 2; ++ct) acc[rt][ct] = (f32x4){0.f, 0.f, 0.f, 0.f};
#pragma unroll
  for (int ks = 0; ks < 3; ++ks) {
    half8 af[6], bf[2];
#pragma unroll
    for (int rt = 0; rt < 6; ++rt)
      af[rt] = *(const half8*)&wsm[(rt * 16 + l15) * 104 + ks * 32 + quad * 8];
#pragma unroll
    for (int ct = 0; ct < 2; ++ct)
      bf[ct] = *(const half8*)&xs[((wid * 2 + ct) * 16 + l15) * 104 + ks * 32 + quad * 8];
#pragma unroll
    for (int rt = 0; rt < 6; ++rt)
#pragma unroll
      for (int ct = 0; ct < 2; ++ct)
        acc[rt][ct] = MFMA16(af[rt], bf[ct], acc[rt][ct], 0, 0, 0);
  }
  __syncthreads();   // xs/wsm reads done -> qs overlay OK
  // q epilogue: logits transposed into qs[n][r]
#pragma unroll
  for (int rt = 0; rt < 6; ++rt)
#pragma unroll
    for (int ct = 0; ct < 2; ++ct)
#pragma unroll
      for (int i = 0; i < 4; ++i) {
        int row = rt * 16 + quad * 4 + i;
        int col = (wid * 2 + ct) * 16 + l15;
        qs[col * 104 + row] = (half_t)acc[rt][ct][i];
      }
  __syncthreads();

  // softmax over head dim: thread owns (token n, head-group hg of 4 heads)
  {
    const int n = tid & 127, hg = tid >> 7;
    half8 v[6];
#pragma unroll
    for (int j = 0; j < 6; ++j)
      v[j] = *(const half8*)&qs[n * 104 + hg * 48 + j * 8];
    float q[48];
#pragma unroll
    for (int j = 0; j < 6; ++j)
#pragma unroll
      for (int e = 0; e < 8; ++e) q[j * 8 + e] = (float)v[j][e];
#pragma unroll
    for (int hh = 0; hh < 4; ++hh) {
      float* ql = q + hh * 12;
      float m = ql[0];
#pragma unroll
      for (int j = 1; j < 12; ++j) m = fmaxf(m, ql[j]);
      float s = 0.f;
#pragma unroll
      for (int j = 0; j < 12; ++j) { ql[j] = __expf(ql[j] - m); s += ql[j]; }
      const float inv = 1.0f / s;
#pragma unroll
      for (int j = 0; j < 12; ++j) ql[j] *= inv;
    }
#pragma unroll
    for (int j = 0; j < 6; ++j) {
      half8 w;
#pragma unroll
      for (int e = 0; e < 8; ++e) w[e] = (half_t)q[j * 8 + e];
      *(half8*)&qs[n * 104 + hg * 48 + j * 8] = w;
    }
  }
  __syncthreads();

  // out GEMM: D[o][n] = sum_r M[o][r] * q[r][n];  B from qs[n][r] (k contiguous)
#pragma unroll
  for (int rt = 0; rt < 6; ++rt)
#pragma unroll
    for (int ct = 0; ct < 2; ++ct) acc[rt][ct] = (f32x4){0.f, 0.f, 0.f, 0.f};
#pragma unroll
  for (int ks = 0; ks < 3; ++ks) {
    half8 af[6], bf[2];
#pragma unroll
    for (int rt = 0; rt < 6; ++rt)
      af[rt] = *(const half8*)&Ms[(rt * 16 + l15) * 104 + ks * 32 + quad * 8];
#pragma unroll
    for (int ct = 0; ct < 2; ++ct)
      bf[ct] = *(const half8*)&qs[((wid * 2 + ct) * 16 + l15) * 104 + ks * 32 + quad * 8];
#pragma unroll
    for (int rt = 0; rt < 6; ++rt)
#pragma unroll
      for (int ct = 0; ct < 2; ++ct)
        acc[rt][ct] = MFMA16(af[rt], bf[ct], acc[rt][ct], 0, 0, 0);
  }
  // store (rows of 16 consecutive floats per lane group; adjacent ct completes 128B lines)
#pragma unroll
  for (int rt = 0; rt < 6; ++rt)
#pragma unroll
    for (int ct = 0; ct < 2; ++ct)
#pragma unroll
      for (int i = 0; i < 4; ++i) {
        int row = rt * 16 + quad * 4 + i;
        int col = (wid * 2 + ct) * 16 + l15;
        out[(((size_t)(b * 96 + row)) << NSH) + n0 + col] = acc[rt][ct][i];
      }
}

extern "C" void kernel_launch(void* const* d_in, const int* in_sizes, int n_in,
                              void* d_out, int out_size, void* d_ws, size_t ws_size,
                              hipStream_t stream) {
  const float* x     = (const float*)d_in[0];
  const float* Wq    = (const float*)d_in[1];
  const float* Wk    = (const float*)d_in[2];
  const float* Wv    = (const float*)d_in[3];
  const float* Wproj = (const float*)d_in[4];
  float* out = (float*)d_out;
  float* ws  = (float*)d_ws;

  float* part = ws;                      // NP*2*1248 floats
  float* Mt   = ws + NP * 2 * 1248;      // 2*96*96 floats

  hipMemsetAsync(part, 0, NP * 2 * 1248 * sizeof(float), stream);
  p1<<<2048, 256, 0, stream>>>(x, Wk, Wv, part);
  kB<<<72, 256, 0, stream>>>(part, Wproj, Mt);
  p3<<<2048, 256, 0, stream>>>(x, Wq, Mt, out);
}